// Round 1
// baseline (1071.484 us; speedup 1.0000x reference)
//
#include <hip/hip_runtime.h>
#include <hip/hip_bf16.h>

#define N_NODES 20000
#define N_EDGES 640000
#define N_GRAPHS 256

__device__ __forceinline__ float leaky02(float x){ return x > 0.f ? x : 0.2f*x; }
__device__ __forceinline__ float eluf(float x){ return x > 0.f ? x : (__expf(x) - 1.f); }

// ---------- scalar prep: c_l = dot(We_l, ae_l) ----------
__global__ void prep_c_kernel(const float* __restrict__ We1, const float* __restrict__ ae1,
                              const float* __restrict__ We2, const float* __restrict__ ae2,
                              const float* __restrict__ We3, const float* __restrict__ ae3,
                              float* __restrict__ scal){
  int tid = threadIdx.x;
  int wv = tid >> 6, lane = tid & 63;
  if (wv < 3){
    const float* We = wv==0 ? We1 : (wv==1 ? We2 : We3);
    const float* ae = wv==0 ? ae1 : (wv==1 ? ae2 : ae3);
    int F = (wv==2) ? 64 : 128;
    float s = 0.f;
    for (int i = lane; i < F; i += 64) s += We[i]*ae[i];
    for (int o = 32; o; o >>= 1) s += __shfl_down(s, o);
    if (lane == 0) scal[2+wv] = s;
  }
}

// ---------- sum of edge_col (for self-loop mean) ----------
__global__ void reduce_sum_kernel(const float* __restrict__ in, int n, float* __restrict__ out){
  float s = 0.f;
  for (int i = blockIdx.x*blockDim.x + threadIdx.x; i < n; i += gridDim.x*blockDim.x) s += in[i];
  for (int o = 32; o; o >>= 1) s += __shfl_down(s, o);
  __shared__ float wred[4];
  int lane = threadIdx.x & 63, wv = threadIdx.x >> 6;
  if (lane == 0) wred[wv] = s;
  __syncthreads();
  if (threadIdx.x == 0){
    float t = 0.f;
    for (int i = 0; i < 4; ++i) t += wred[i];
    atomicAdd(out, t);
  }
}

// ---------- CSR build ----------
__global__ void count_deg_kernel(const int* __restrict__ dst, int* __restrict__ deg){
  int i = blockIdx.x*blockDim.x + threadIdx.x;
  if (i < N_EDGES) atomicAdd(&deg[dst[i]], 1);
}

__global__ void scan_kernel(const int* __restrict__ deg, int* __restrict__ row_ptr, int* __restrict__ cursor){
  __shared__ int sums[1024];
  int tid = threadIdx.x;
  const int CH = (N_NODES + 1023)/1024; // 20
  int base = tid*CH;
  int s = 0;
  #pragma unroll
  for (int i = 0; i < CH; ++i){ int idx = base+i; if (idx < N_NODES) s += deg[idx]; }
  sums[tid] = s;
  __syncthreads();
  for (int d = 1; d < 1024; d <<= 1){
    int v = (tid >= d) ? sums[tid-d] : 0;
    __syncthreads();
    sums[tid] += v;
    __syncthreads();
  }
  int off = sums[tid] - s; // exclusive prefix
  for (int i = 0; i < CH; ++i){
    int idx = base+i;
    if (idx < N_NODES){ int c = deg[idx]; row_ptr[idx] = off; cursor[idx] = off; off += c; }
  }
  if (tid == 1023) row_ptr[N_NODES] = sums[1023];
}

__global__ void scatter_kernel(const int* __restrict__ src, const int* __restrict__ dst,
                               const float* __restrict__ ea, int* __restrict__ cursor,
                               int2* __restrict__ edges){
  int i = blockIdx.x*blockDim.x + threadIdx.x;
  if (i < N_EDGES){
    int d = dst[i];
    int pos = atomicAdd(&cursor[d], 1);
    edges[pos] = make_int2(src[i], __float_as_int(ea[i]));
  }
}

// ---------- node-wise GEMM h = x@W (+ fused a_s, a_d row dots) ----------
// K-slice [KOFF, KOFF+KLEN) so static LDS stays <= 33KB.
template<int K, int F, int KOFF, int KLEN, bool FIRST, bool DOATT>
__global__ __launch_bounds__(256) void node_linear_kernel(
    const float* __restrict__ x, const float* __restrict__ W,
    const float* __restrict__ atts, const float* __restrict__ attd,
    float* __restrict__ h, float* __restrict__ a_s, float* __restrict__ a_d)
{
  constexpr int ROWS = 256 / F; // 2 (F=128) or 4 (F=64)
  __shared__ float Wl[KLEN*F];
  __shared__ float xl[ROWS*KLEN];
  __shared__ float swv[4], dwv[4];
  int tid = threadIdx.x;
  for (int i = tid; i < KLEN*F; i += 256) Wl[i] = W[KOFF*F + i];
  int f = tid % F;
  int lr = tid / F;
  float vs = DOATT ? atts[f] : 0.f;
  float vd = DOATT ? attd[f] : 0.f;
  const int ntiles = (N_NODES + ROWS - 1)/ROWS;
  for (int t = blockIdx.x; t < ntiles; t += gridDim.x){
    int r0 = t*ROWS;
    __syncthreads();
    for (int i = tid; i < ROWS*KLEN; i += 256){
      int r = i / KLEN, k = i % KLEN;
      int row = r0 + r;
      xl[i] = (row < N_NODES) ? x[row*K + KOFF + k] : 0.f;
    }
    __syncthreads();
    float acc = 0.f;
    #pragma unroll
    for (int k = 0; k < KLEN; ++k) acc += xl[lr*KLEN + k] * Wl[k*F + f];
    int row = r0 + lr;
    if (row < N_NODES){
      if (!FIRST) acc += h[row*F + f];
      h[row*F + f] = acc;
    }
    if (DOATT){
      float s = acc*vs, d = acc*vd;
      #pragma unroll
      for (int o = 32; o; o >>= 1){ s += __shfl_down(s, o); d += __shfl_down(d, o); }
      int wv = tid >> 6;
      if ((tid & 63) == 0){ swv[wv] = s; dwv[wv] = d; }
      __syncthreads();
      if (f == 0 && row < N_NODES){
        if (F == 128){ a_s[row] = swv[2*lr] + swv[2*lr+1]; a_d[row] = dwv[2*lr] + dwv[2*lr+1]; }
        else         { a_s[row] = swv[lr];                 a_d[row] = dwv[lr]; }
      }
    }
  }
}

// ---------- per-dst online-softmax aggregation + bias + ELU ----------
template<int F>
__global__ __launch_bounds__(256) void aggregate_kernel(
    const float* __restrict__ h, const float* __restrict__ a_s, const float* __restrict__ a_d,
    const int2* __restrict__ edges, const int* __restrict__ row_ptr,
    const float* __restrict__ scal, int b, int l,
    const float* __restrict__ bias, float* __restrict__ out)
{
  int wv = threadIdx.x >> 6;
  int lane = threadIdx.x & 63;
  int d = blockIdx.x*4 + wv;
  if (d >= N_NODES) return;
  float c = scal[2+l];
  float ae_self = (scal[b] * (1.0f/N_EDGES)) * c;
  float add_ = a_d[d];
  constexpr int PER = F/64; // 2 (F=128) or 1 (F=64)
  // self-loop seeds the online softmax: p=1, denom=1, acc=h[d]
  float m = leaky02(a_s[d] + add_ + ae_self);
  float denom = 1.0f;
  float acc[PER];
  #pragma unroll
  for (int i = 0; i < PER; ++i) acc[i] = h[d*F + PER*lane + i];
  int e0 = row_ptr[d], e1 = row_ptr[d+1];
  for (int e = e0; e < e1; ++e){
    int2 ed = edges[e];
    int src = ed.x;
    float ea = __int_as_float(ed.y);
    float logit = leaky02(a_s[src] + add_ + c*ea);
    if (logit > m){
      float sc = __expf(m - logit);
      denom *= sc;
      #pragma unroll
      for (int i = 0; i < PER; ++i) acc[i] *= sc;
      m = logit;
    }
    float p = __expf(logit - m);
    denom += p;
    const float* hs = &h[src*F + PER*lane];
    #pragma unroll
    for (int i = 0; i < PER; ++i) acc[i] += p * hs[i];
  }
  float inv = 1.0f/denom;
  #pragma unroll
  for (int i = 0; i < PER; ++i){
    float v = acc[i]*inv + bias[PER*lane + i];
    out[d*F + PER*lane + i] = eluf(v);
  }
}

// ---------- mean pool (atomics) ----------
__global__ void pool_kernel(const float* __restrict__ x, const int* __restrict__ batch,
                            float* __restrict__ pool, float* __restrict__ cnt){
  int i = blockIdx.x*blockDim.x + threadIdx.x;
  if (i >= N_NODES*64) return;
  int node = i >> 6, f = i & 63;
  int g = batch[node];
  atomicAdd(&pool[g*64 + f], x[node*64 + f]);
  if (f == 0) atomicAdd(&cnt[g], 1.0f);
}

// ---------- final linear: concat(pool/cnt, x_norm2) @ linW + linb ----------
__global__ void final_kernel(const float* __restrict__ pool, const float* __restrict__ cnt,
                             const float* __restrict__ xn, const float* __restrict__ linW,
                             const float* __restrict__ linb, float* __restrict__ out){
  __shared__ float Wl[80*64];
  int tid = threadIdx.x;
  for (int i = tid; i < 80*64; i += 256) Wl[i] = linW[i];
  __syncthreads();
  int gl = tid >> 6, j = tid & 63;
  int g = blockIdx.x*4 + gl;
  if (g >= N_GRAPHS) return;
  float invc = 1.0f / fmaxf(cnt[g], 1.0f);
  float acc = linb[j];
  #pragma unroll 8
  for (int k = 0; k < 64; ++k) acc += (pool[g*64+k]*invc) * Wl[k*64 + j];
  #pragma unroll
  for (int k = 0; k < 16; ++k) acc += xn[g*16+k] * Wl[(64+k)*64 + j];
  out[g*64 + j] = acc;
}

extern "C" void kernel_launch(void* const* d_in, const int* in_sizes, int n_in,
                              void* d_out, int out_size, void* d_ws, size_t ws_size,
                              hipStream_t stream)
{
  const float* x1   = (const float*)d_in[0];
  const float* x2   = (const float*)d_in[1];
  const int*   ei1  = (const int*)d_in[2];
  const int*   ei2  = (const int*)d_in[3];
  const int*   bat1 = (const int*)d_in[4];
  const int*   bat2 = (const int*)d_in[5];
  const float* xn1  = (const float*)d_in[6];
  const float* xn2  = (const float*)d_in[7];
  const float* ec1  = (const float*)d_in[8];
  const float* ec2  = (const float*)d_in[9];
  const float* W[3]   = {(const float*)d_in[10], (const float*)d_in[16], (const float*)d_in[22]};
  const float* as_[3] = {(const float*)d_in[11], (const float*)d_in[17], (const float*)d_in[23]};
  const float* ad_[3] = {(const float*)d_in[12], (const float*)d_in[18], (const float*)d_in[24]};
  const float* We[3]  = {(const float*)d_in[13], (const float*)d_in[19], (const float*)d_in[25]};
  const float* ae[3]  = {(const float*)d_in[14], (const float*)d_in[20], (const float*)d_in[26]};
  const float* bb[3]  = {(const float*)d_in[15], (const float*)d_in[21], (const float*)d_in[27]};
  const float* linW = (const float*)d_in[28];
  const float* linb = (const float*)d_in[29];
  float* out = (float*)d_out;

  char* ws = (char*)d_ws;
  size_t off = 0;
  auto alloc = [&](size_t bytes)->char*{
    char* p = ws + off;
    off = (off + bytes + 255) & ~(size_t)255;
    return p;
  };
  float* buf0[2]; float* bufH[2]; float* aS[2]; float* aD[2];
  int* deg[2]; int* rowp[2]; int* cur[2]; int2* edg[2]; float* pool[2]; float* cnt[2];
  for (int b = 0; b < 2; ++b){
    buf0[b] = (float*)alloc((size_t)N_NODES*128*4);
    bufH[b] = (float*)alloc((size_t)N_NODES*128*4);
    aS[b]   = (float*)alloc((size_t)N_NODES*4);
    aD[b]   = (float*)alloc((size_t)N_NODES*4);
    deg[b]  = (int*)alloc((size_t)N_NODES*4);
    rowp[b] = (int*)alloc((size_t)(N_NODES+4)*4);
    cur[b]  = (int*)alloc((size_t)N_NODES*4);
    edg[b]  = (int2*)alloc((size_t)N_EDGES*8);
    pool[b] = (float*)alloc((size_t)N_GRAPHS*64*4);
    cnt[b]  = (float*)alloc((size_t)N_GRAPHS*4);
  }
  float* scal = (float*)alloc(64);

  for (int b = 0; b < 2; ++b){
    hipMemsetAsync(deg[b],  0, (size_t)N_NODES*4, stream);
    hipMemsetAsync(pool[b], 0, (size_t)N_GRAPHS*64*4, stream);
    hipMemsetAsync(cnt[b],  0, (size_t)N_GRAPHS*4, stream);
  }
  hipMemsetAsync(scal, 0, 64, stream);

  prep_c_kernel<<<1, 256, 0, stream>>>(We[0], ae[0], We[1], ae[1], We[2], ae[2], scal);

  const float* xin[2]  = {x1, x2};
  const int*   ei[2]   = {ei1, ei2};
  const int*   bat[2]  = {bat1, bat2};
  const float* xn[2]   = {xn1, xn2};
  const float* ec[2]   = {ec1, ec2};

  for (int b = 0; b < 2; ++b){
    const int* srcp = ei[b];
    const int* dstp = ei[b] + N_EDGES;
    reduce_sum_kernel<<<1024, 256, 0, stream>>>(ec[b], N_EDGES, scal + b);
    count_deg_kernel<<<(N_EDGES+255)/256, 256, 0, stream>>>(dstp, deg[b]);
    scan_kernel<<<1, 1024, 0, stream>>>(deg[b], rowp[b], cur[b]);
    scatter_kernel<<<(N_EDGES+255)/256, 256, 0, stream>>>(srcp, dstp, ec[b], cur[b], edg[b]);

    // layer 1: K=7 -> F=128
    node_linear_kernel<7,128,0,7,true,true><<<1024, 256, 0, stream>>>(
        xin[b], W[0], as_[0], ad_[0], bufH[b], aS[b], aD[b]);
    aggregate_kernel<128><<<N_NODES/4, 256, 0, stream>>>(
        bufH[b], aS[b], aD[b], edg[b], rowp[b], scal, b, 0, bb[0], buf0[b]);

    // layer 2: K=128 -> F=128 (two K-halves to keep LDS <= 33KB)
    node_linear_kernel<128,128,0,64,true,false><<<2048, 256, 0, stream>>>(
        buf0[b], W[1], as_[1], ad_[1], bufH[b], aS[b], aD[b]);
    node_linear_kernel<128,128,64,64,false,true><<<2048, 256, 0, stream>>>(
        buf0[b], W[1], as_[1], ad_[1], bufH[b], aS[b], aD[b]);
    aggregate_kernel<128><<<N_NODES/4, 256, 0, stream>>>(
        bufH[b], aS[b], aD[b], edg[b], rowp[b], scal, b, 1, bb[1], buf0[b]);

    // layer 3: K=128 -> F=64 (Wl = 32KB, single pass)
    node_linear_kernel<128,64,0,128,true,true><<<2048, 256, 0, stream>>>(
        buf0[b], W[2], as_[2], ad_[2], bufH[b], aS[b], aD[b]);
    aggregate_kernel<64><<<N_NODES/4, 256, 0, stream>>>(
        bufH[b], aS[b], aD[b], edg[b], rowp[b], scal, b, 2, bb[2], buf0[b]);

    pool_kernel<<<(N_NODES*64+255)/256, 256, 0, stream>>>(buf0[b], bat[b], pool[b], cnt[b]);
    final_kernel<<<(N_GRAPHS+3)/4, 256, 0, stream>>>(pool[b], cnt[b], xn[b], linW, linb, out + (size_t)b*N_GRAPHS*64);
  }
}

// Round 2
// 743.080 us; speedup vs baseline: 1.4420x; 1.4420x over previous
//
#include <hip/hip_runtime.h>
#include <hip/hip_bf16.h>

#define N_NODES 20000
#define N_EDGES 640000
#define N_GRAPHS 256

__device__ __forceinline__ float leaky02(float x){ return x > 0.f ? x : 0.2f*x; }
__device__ __forceinline__ float eluf(float x){ return x > 0.f ? x : (__expf(x) - 1.f); }

// ---------- scalar prep: c_l = dot(We_l, ae_l) ----------
__global__ void prep_c_kernel(const float* __restrict__ We1, const float* __restrict__ ae1,
                              const float* __restrict__ We2, const float* __restrict__ ae2,
                              const float* __restrict__ We3, const float* __restrict__ ae3,
                              float* __restrict__ scal){
  int tid = threadIdx.x;
  int wv = tid >> 6, lane = tid & 63;
  if (wv < 3){
    const float* We = wv==0 ? We1 : (wv==1 ? We2 : We3);
    const float* ae = wv==0 ? ae1 : (wv==1 ? ae2 : ae3);
    int F = (wv==2) ? 64 : 128;
    float s = 0.f;
    for (int i = lane; i < F; i += 64) s += We[i]*ae[i];
    for (int o = 32; o; o >>= 1) s += __shfl_down(s, o);
    if (lane == 0) scal[2+wv] = s;
  }
}

// ---------- sum of edge_col (for self-loop mean) ----------
__global__ void reduce_sum_kernel(const float* __restrict__ in, int n, float* __restrict__ out){
  float s = 0.f;
  for (int i = blockIdx.x*blockDim.x + threadIdx.x; i < n; i += gridDim.x*blockDim.x) s += in[i];
  for (int o = 32; o; o >>= 1) s += __shfl_down(s, o);
  __shared__ float wred[4];
  int lane = threadIdx.x & 63, wv = threadIdx.x >> 6;
  if (lane == 0) wred[wv] = s;
  __syncthreads();
  if (threadIdx.x == 0){
    float t = 0.f;
    for (int i = 0; i < 4; ++i) t += wred[i];
    atomicAdd(out, t);
  }
}

// ---------- CSR build ----------
__global__ void count_deg_kernel(const int* __restrict__ dst, int* __restrict__ deg){
  int i = blockIdx.x*blockDim.x + threadIdx.x;
  if (i < N_EDGES) atomicAdd(&deg[dst[i]], 1);
}

__global__ void scan_kernel(const int* __restrict__ deg, int* __restrict__ row_ptr, int* __restrict__ cursor){
  __shared__ int sums[1024];
  int tid = threadIdx.x;
  const int CH = (N_NODES + 1023)/1024; // 20
  int base = tid*CH;
  int s = 0;
  #pragma unroll
  for (int i = 0; i < CH; ++i){ int idx = base+i; if (idx < N_NODES) s += deg[idx]; }
  sums[tid] = s;
  __syncthreads();
  for (int d = 1; d < 1024; d <<= 1){
    int v = (tid >= d) ? sums[tid-d] : 0;
    __syncthreads();
    sums[tid] += v;
    __syncthreads();
  }
  int off = sums[tid] - s; // exclusive prefix
  for (int i = 0; i < CH; ++i){
    int idx = base+i;
    if (idx < N_NODES){ int c = deg[idx]; row_ptr[idx] = off; cursor[idx] = off; off += c; }
  }
  if (tid == 1023) row_ptr[N_NODES] = sums[1023];
}

__global__ void scatter_kernel(const int* __restrict__ src, const int* __restrict__ dst,
                               const float* __restrict__ ea, int* __restrict__ cursor,
                               int2* __restrict__ edges){
  int i = blockIdx.x*blockDim.x + threadIdx.x;
  if (i < N_EDGES){
    int d = dst[i];
    int pos = atomicAdd(&cursor[d], 1);
    edges[pos] = make_int2(src[i], __float_as_int(ea[i]));
  }
}

// ---------- node-wise GEMM h = x@W (+ fused a_s, a_d row dots) ----------
// Final pass (DOATT) writes bf16 h for the gather phase; partial passes write f32.
template<int K, int F, int KOFF, int KLEN, bool FIRST, bool DOATT>
__global__ __launch_bounds__(256) void node_linear_kernel(
    const float* __restrict__ x, const float* __restrict__ W,
    const float* __restrict__ atts, const float* __restrict__ attd,
    float* __restrict__ h, __hip_bfloat16* __restrict__ hb,
    float* __restrict__ a_s, float* __restrict__ a_d)
{
  constexpr int ROWS = 256 / F; // 2 (F=128) or 4 (F=64)
  __shared__ float Wl[KLEN*F];
  __shared__ float xl[ROWS*KLEN];
  __shared__ float swv[4], dwv[4];
  int tid = threadIdx.x;
  for (int i = tid; i < KLEN*F; i += 256) Wl[i] = W[KOFF*F + i];
  int f = tid % F;
  int lr = tid / F;
  float vs = DOATT ? atts[f] : 0.f;
  float vd = DOATT ? attd[f] : 0.f;
  const int ntiles = (N_NODES + ROWS - 1)/ROWS;
  for (int t = blockIdx.x; t < ntiles; t += gridDim.x){
    int r0 = t*ROWS;
    __syncthreads();
    for (int i = tid; i < ROWS*KLEN; i += 256){
      int r = i / KLEN, k = i % KLEN;
      int row = r0 + r;
      xl[i] = (row < N_NODES) ? x[row*K + KOFF + k] : 0.f;
    }
    __syncthreads();
    float acc = 0.f;
    #pragma unroll
    for (int k = 0; k < KLEN; ++k) acc += xl[lr*KLEN + k] * Wl[k*F + f];
    int row = r0 + lr;
    if (row < N_NODES){
      if (!FIRST) acc += h[row*F + f];
      if (DOATT) hb[row*F + f] = __float2bfloat16(acc);
      else       h[row*F + f] = acc;
    }
    if (DOATT){
      float s = acc*vs, d = acc*vd;
      #pragma unroll
      for (int o = 32; o; o >>= 1){ s += __shfl_down(s, o); d += __shfl_down(d, o); }
      int wv = tid >> 6;
      if ((tid & 63) == 0){ swv[wv] = s; dwv[wv] = d; }
      __syncthreads();
      if (f == 0 && row < N_NODES){
        if (F == 128){ a_s[row] = swv[2*lr] + swv[2*lr+1]; a_d[row] = dwv[2*lr] + dwv[2*lr+1]; }
        else         { a_s[row] = swv[lr];                 a_d[row] = dwv[lr]; }
      }
    }
  }
}

// ---------- per-dst two-phase softmax aggregation + bias + ELU ----------
// One wave per dst. Phase 1: 64 lanes compute chunk logits in parallel,
// shfl_xor reductions for max/denom. Phase 2: branch-free p*h gather (bf16).
template<int F>
__global__ __launch_bounds__(256) void aggregate_kernel(
    const float* __restrict__ h32, const __hip_bfloat16* __restrict__ hb,
    const float* __restrict__ a_s, const float* __restrict__ a_d,
    const int2* __restrict__ edges, const int* __restrict__ row_ptr,
    const float* __restrict__ scal, int b, int l,
    const float* __restrict__ bias, float* __restrict__ out)
{
  int wv = threadIdx.x >> 6;
  int lane = threadIdx.x & 63;
  int d = blockIdx.x*4 + wv;
  if (d >= N_NODES) return;
  float c = scal[2+l];
  float ae_self = (scal[b] * (1.0f/N_EDGES)) * c;
  float add_ = a_d[d];
  constexpr int PER = F/64; // 2 (F=128) or 1 (F=64)
  // self-loop seeds: p_self = e^0 = 1
  float m = leaky02(a_s[d] + add_ + ae_self);
  float denom = 1.0f;
  float acc[PER];
  #pragma unroll
  for (int i = 0; i < PER; ++i) acc[i] = h32[d*F + PER*lane + i];
  int e0 = row_ptr[d], e1 = row_ptr[d+1];
  for (int ch = e0; ch < e1; ch += 128){
    int n = min(128, e1 - ch);
    // ---- phase 1: parallel logits ----
    int s0 = 0, s1 = 0;
    float l0 = -1e30f, l1 = -1e30f;
    if (lane < n){
      int2 ed = edges[ch + lane];
      s0 = ed.x;
      l0 = leaky02(a_s[ed.x] + add_ + c*__int_as_float(ed.y));
    }
    if (lane + 64 < n){
      int2 ed = edges[ch + 64 + lane];
      s1 = ed.x;
      l1 = leaky02(a_s[ed.x] + add_ + c*__int_as_float(ed.y));
    }
    float lmax = fmaxf(l0, l1);
    #pragma unroll
    for (int o = 32; o; o >>= 1) lmax = fmaxf(lmax, __shfl_xor(lmax, o));
    float mn = fmaxf(m, lmax);
    float sc = __expf(m - mn);
    denom *= sc;
    #pragma unroll
    for (int i = 0; i < PER; ++i) acc[i] *= sc;
    m = mn;
    float p0 = (lane < n)      ? __expf(l0 - m) : 0.f;
    float p1 = (lane + 64 < n) ? __expf(l1 - m) : 0.f;
    float ds = p0 + p1;
    #pragma unroll
    for (int o = 32; o; o >>= 1) ds += __shfl_xor(ds, o);
    denom += ds;
    // ---- phase 2: branch-free gather-accumulate ----
    int n0 = min(n, 64);
    for (int j = 0; j < n0; ++j){
      int src = __shfl(s0, j);
      float p = __shfl(p0, j);
      if (PER == 2){
        unsigned int v = *reinterpret_cast<const unsigned int*>(&hb[src*F + 2*lane]);
        acc[0] += p * __uint_as_float(v << 16);
        acc[1] += p * __uint_as_float(v & 0xffff0000u);
      } else {
        unsigned short u = *reinterpret_cast<const unsigned short*>(&hb[src*F + lane]);
        acc[0] += p * __uint_as_float(((unsigned int)u) << 16);
      }
    }
    for (int j = 64; j < n; ++j){
      int src = __shfl(s1, j - 64);
      float p = __shfl(p1, j - 64);
      if (PER == 2){
        unsigned int v = *reinterpret_cast<const unsigned int*>(&hb[src*F + 2*lane]);
        acc[0] += p * __uint_as_float(v << 16);
        acc[1] += p * __uint_as_float(v & 0xffff0000u);
      } else {
        unsigned short u = *reinterpret_cast<const unsigned short*>(&hb[src*F + lane]);
        acc[0] += p * __uint_as_float(((unsigned int)u) << 16);
      }
    }
  }
  float inv = 1.0f/denom;
  #pragma unroll
  for (int i = 0; i < PER; ++i){
    float v = acc[i]*inv + bias[PER*lane + i];
    out[d*F + PER*lane + i] = eluf(v);
  }
}

// aggregate seeds read f32 self row only for layer-2 partial path; for final
// layers we seed from bf16 via a tiny wrapper: keep one h32 buffer filled by
// copy? -> Instead we seed from bf16 too (error identical class to neighbors).
template<int F>
__global__ __launch_bounds__(256) void seed_copy_kernel(const __hip_bfloat16* __restrict__ hb,
                                                        float* __restrict__ h32){
  int i = blockIdx.x*blockDim.x + threadIdx.x;
  if (i < N_NODES*F) h32[i] = __bfloat162float(hb[i]);
}

// ---------- sorted-batch graph boundaries ----------
__global__ void bounds_kernel(const int* __restrict__ batch, int* __restrict__ gb){
  int g = blockIdx.x*blockDim.x + threadIdx.x;
  if (g > N_GRAPHS) return;
  int lo = 0, hi = N_NODES;
  while (lo < hi){ int mid = (lo+hi) >> 1; if (batch[mid] < g) lo = mid+1; else hi = mid; }
  gb[g] = lo;
}

// ---------- mean pool over contiguous row ranges ----------
__global__ __launch_bounds__(256) void pool_mean_kernel(const float* __restrict__ x,
                                                        const int* __restrict__ gb,
                                                        float* __restrict__ mean){
  int g = blockIdx.x;
  int s = gb[g], e = gb[g+1];
  int f = threadIdx.x & 63, rg = threadIdx.x >> 6;
  float acc = 0.f;
  for (int r = s + rg; r < e; r += 4) acc += x[r*64 + f];
  __shared__ float red[4][64];
  red[rg][f] = acc;
  __syncthreads();
  if (rg == 0){
    float t = red[0][f] + red[1][f] + red[2][f] + red[3][f];
    mean[g*64 + f] = t / fmaxf((float)(e - s), 1.0f);
  }
}

// ---------- final linear: concat(mean, x_norm2) @ linW + linb ----------
__global__ void final_kernel(const float* __restrict__ mean,
                             const float* __restrict__ xn, const float* __restrict__ linW,
                             const float* __restrict__ linb, float* __restrict__ out){
  __shared__ float Wl[80*64];
  int tid = threadIdx.x;
  for (int i = tid; i < 80*64; i += 256) Wl[i] = linW[i];
  __syncthreads();
  int gl = tid >> 6, j = tid & 63;
  int g = blockIdx.x*4 + gl;
  if (g >= N_GRAPHS) return;
  float acc = linb[j];
  #pragma unroll 8
  for (int k = 0; k < 64; ++k) acc += mean[g*64+k] * Wl[k*64 + j];
  #pragma unroll
  for (int k = 0; k < 16; ++k) acc += xn[g*16+k] * Wl[(64+k)*64 + j];
  out[g*64 + j] = acc;
}

extern "C" void kernel_launch(void* const* d_in, const int* in_sizes, int n_in,
                              void* d_out, int out_size, void* d_ws, size_t ws_size,
                              hipStream_t stream)
{
  const float* x1   = (const float*)d_in[0];
  const float* x2   = (const float*)d_in[1];
  const int*   ei1  = (const int*)d_in[2];
  const int*   ei2  = (const int*)d_in[3];
  const int*   bat1 = (const int*)d_in[4];
  const int*   bat2 = (const int*)d_in[5];
  const float* xn1  = (const float*)d_in[6];
  const float* xn2  = (const float*)d_in[7];
  const float* ec1  = (const float*)d_in[8];
  const float* ec2  = (const float*)d_in[9];
  const float* W[3]   = {(const float*)d_in[10], (const float*)d_in[16], (const float*)d_in[22]};
  const float* as_[3] = {(const float*)d_in[11], (const float*)d_in[17], (const float*)d_in[23]};
  const float* ad_[3] = {(const float*)d_in[12], (const float*)d_in[18], (const float*)d_in[24]};
  const float* We[3]  = {(const float*)d_in[13], (const float*)d_in[19], (const float*)d_in[25]};
  const float* ae[3]  = {(const float*)d_in[14], (const float*)d_in[20], (const float*)d_in[26]};
  const float* bb[3]  = {(const float*)d_in[15], (const float*)d_in[21], (const float*)d_in[27]};
  const float* linW = (const float*)d_in[28];
  const float* linb = (const float*)d_in[29];
  float* out = (float*)d_out;

  char* ws = (char*)d_ws;
  size_t off = 0;
  auto alloc = [&](size_t bytes)->char*{
    char* p = ws + off;
    off = (off + bytes + 255) & ~(size_t)255;
    return p;
  };
  // single buffer set, reused by both (sequential) branches
  float* buf0 = (float*)alloc((size_t)N_NODES*128*4);   // layer input / aggregate output
  float* bufH = (float*)alloc((size_t)N_NODES*128*4);   // f32 partial (layer-2 RMW) + seed
  __hip_bfloat16* hb = (__hip_bfloat16*)alloc((size_t)N_NODES*128*2); // bf16 gather copy
  float* aS   = (float*)alloc((size_t)N_NODES*4);
  float* aD   = (float*)alloc((size_t)N_NODES*4);
  int* deg    = (int*)alloc((size_t)N_NODES*4);
  int* rowp   = (int*)alloc((size_t)(N_NODES+4)*4);
  int* cur    = (int*)alloc((size_t)N_NODES*4);
  int2* edg   = (int2*)alloc((size_t)N_EDGES*8);
  float* mean = (float*)alloc((size_t)N_GRAPHS*64*4);
  int* gb     = (int*)alloc((size_t)(N_GRAPHS+8)*4);
  float* scal = (float*)alloc(64);

  hipMemsetAsync(scal, 0, 64, stream);
  prep_c_kernel<<<1, 256, 0, stream>>>(We[0], ae[0], We[1], ae[1], We[2], ae[2], scal);

  const float* xin[2]  = {x1, x2};
  const int*   ei[2]   = {ei1, ei2};
  const int*   bat[2]  = {bat1, bat2};
  const float* xn[2]   = {xn1, xn2};
  const float* ec[2]   = {ec1, ec2};

  for (int b = 0; b < 2; ++b){
    const int* srcp = ei[b];
    const int* dstp = ei[b] + N_EDGES;
    hipMemsetAsync(deg, 0, (size_t)N_NODES*4, stream);
    reduce_sum_kernel<<<1024, 256, 0, stream>>>(ec[b], N_EDGES, scal + b);
    count_deg_kernel<<<(N_EDGES+255)/256, 256, 0, stream>>>(dstp, deg);
    scan_kernel<<<1, 1024, 0, stream>>>(deg, rowp, cur);
    scatter_kernel<<<(N_EDGES+255)/256, 256, 0, stream>>>(srcp, dstp, ec[b], cur, edg);
    bounds_kernel<<<2, 256, 0, stream>>>(bat[b], gb);

    // layer 1: K=7 -> F=128 (bf16 h out + seed copy)
    node_linear_kernel<7,128,0,7,true,true><<<1024, 256, 0, stream>>>(
        xin[b], W[0], as_[0], ad_[0], bufH, hb, aS, aD);
    seed_copy_kernel<128><<<(N_NODES*128+255)/256, 256, 0, stream>>>(hb, bufH);
    aggregate_kernel<128><<<N_NODES/4, 256, 0, stream>>>(
        bufH, hb, aS, aD, edg, rowp, scal, b, 0, bb[0], buf0);

    // layer 2: K=128 -> F=128 (two K-halves; second writes bf16)
    node_linear_kernel<128,128,0,64,true,false><<<2048, 256, 0, stream>>>(
        buf0, W[1], as_[1], ad_[1], bufH, hb, aS, aD);
    node_linear_kernel<128,128,64,64,false,true><<<2048, 256, 0, stream>>>(
        buf0, W[1], as_[1], ad_[1], bufH, hb, aS, aD);
    seed_copy_kernel<128><<<(N_NODES*128+255)/256, 256, 0, stream>>>(hb, bufH);
    aggregate_kernel<128><<<N_NODES/4, 256, 0, stream>>>(
        bufH, hb, aS, aD, edg, rowp, scal, b, 1, bb[1], buf0);

    // layer 3: K=128 -> F=64
    node_linear_kernel<128,64,0,128,true,true><<<2048, 256, 0, stream>>>(
        buf0, W[2], as_[2], ad_[2], bufH, hb, aS, aD);
    seed_copy_kernel<64><<<(N_NODES*64+255)/256, 256, 0, stream>>>(hb, bufH);
    aggregate_kernel<64><<<N_NODES/4, 256, 0, stream>>>(
        bufH, hb, aS, aD, edg, rowp, scal, b, 2, bb[2], buf0);

    pool_mean_kernel<<<N_GRAPHS, 256, 0, stream>>>(buf0, gb, mean);
    final_kernel<<<(N_GRAPHS+3)/4, 256, 0, stream>>>(mean, xn[b], linW, linb, out + (size_t)b*N_GRAPHS*64);
  }
}

// Round 3
// 547.009 us; speedup vs baseline: 1.9588x; 1.3584x over previous
//
#include <hip/hip_runtime.h>
#include <hip/hip_bf16.h>

#define N_NODES 20000
#define N_EDGES 640000
#define N_GRAPHS 256

typedef short bf16v __attribute__((ext_vector_type(8)));   // 8 bf16 (4 VGPRs)
typedef float f32x4 __attribute__((ext_vector_type(4)));

__device__ __forceinline__ float leaky02(float x){ return x > 0.f ? x : 0.2f*x; }
__device__ __forceinline__ float eluf(float x){ return x > 0.f ? x : (__expf(x) - 1.f); }
__device__ __forceinline__ unsigned short f2bf(float x){
  __hip_bfloat16 t = __float2bfloat16(x);
  return *reinterpret_cast<unsigned short*>(&t);
}
__device__ __forceinline__ float bflo(unsigned int u){ return __uint_as_float(u << 16); }
__device__ __forceinline__ float bfhi(unsigned int u){ return __uint_as_float(u & 0xffff0000u); }

// ---------- scalar prep: c_l = dot(We_l, ae_l) ----------
__global__ void prep_c_kernel(const float* __restrict__ We1, const float* __restrict__ ae1,
                              const float* __restrict__ We2, const float* __restrict__ ae2,
                              const float* __restrict__ We3, const float* __restrict__ ae3,
                              float* __restrict__ scal){
  int tid = threadIdx.x;
  int wv = tid >> 6, lane = tid & 63;
  if (wv < 3){
    const float* We = wv==0 ? We1 : (wv==1 ? We2 : We3);
    const float* ae = wv==0 ? ae1 : (wv==1 ? ae2 : ae3);
    int F = (wv==2) ? 64 : 128;
    float s = 0.f;
    for (int i = lane; i < F; i += 64) s += We[i]*ae[i];
    for (int o = 32; o; o >>= 1) s += __shfl_down(s, o);
    if (lane == 0) scal[2+wv] = s;
  }
}

__global__ void reduce_sum_kernel(const float* __restrict__ in, int n, float* __restrict__ out){
  float s = 0.f;
  for (int i = blockIdx.x*blockDim.x + threadIdx.x; i < n; i += gridDim.x*blockDim.x) s += in[i];
  for (int o = 32; o; o >>= 1) s += __shfl_down(s, o);
  __shared__ float wred[4];
  int lane = threadIdx.x & 63, wv = threadIdx.x >> 6;
  if (lane == 0) wred[wv] = s;
  __syncthreads();
  if (threadIdx.x == 0){
    float t = 0.f;
    for (int i = 0; i < 4; ++i) t += wred[i];
    atomicAdd(out, t);
  }
}

// ---------- CSR build ----------
__global__ void count_deg_kernel(const int* __restrict__ dst, int* __restrict__ deg){
  int i = blockIdx.x*blockDim.x + threadIdx.x;
  if (i < N_EDGES) atomicAdd(&deg[dst[i]], 1);
}

__global__ void scan_kernel(const int* __restrict__ deg, int* __restrict__ row_ptr, int* __restrict__ cursor){
  __shared__ int sums[1024];
  int tid = threadIdx.x;
  const int CH = (N_NODES + 1023)/1024; // 20
  int base = tid*CH;
  int s = 0;
  #pragma unroll
  for (int i = 0; i < CH; ++i){ int idx = base+i; if (idx < N_NODES) s += deg[idx]; }
  sums[tid] = s;
  __syncthreads();
  for (int d = 1; d < 1024; d <<= 1){
    int v = (tid >= d) ? sums[tid-d] : 0;
    __syncthreads();
    sums[tid] += v;
    __syncthreads();
  }
  int off = sums[tid] - s;
  for (int i = 0; i < CH; ++i){
    int idx = base+i;
    if (idx < N_NODES){ int c = deg[idx]; row_ptr[idx] = off; cursor[idx] = off; off += c; }
  }
  if (tid == 1023) row_ptr[N_NODES] = sums[1023];
}

__global__ void scatter_kernel(const int* __restrict__ src, const int* __restrict__ dst,
                               const float* __restrict__ ea, int* __restrict__ cursor,
                               int2* __restrict__ edges){
  int i = blockIdx.x*blockDim.x + threadIdx.x;
  if (i < N_EDGES){
    int d = dst[i];
    int pos = atomicAdd(&cursor[d], 1);
    edges[pos] = make_int2(src[i], __float_as_int(ea[i]));
  }
}

// ---------- layer 1: K=7 scalar GEMM + att dots, bf16 out ----------
template<int K, int F>
__global__ __launch_bounds__(256) void node_linear1_kernel(
    const float* __restrict__ x, const float* __restrict__ W,
    const float* __restrict__ atts, const float* __restrict__ attd,
    unsigned short* __restrict__ hb, float* __restrict__ a_s, float* __restrict__ a_d)
{
  constexpr int ROWS = 256 / F; // 2
  __shared__ float Wl[K*F];
  __shared__ float xl[ROWS*K];
  __shared__ float swv[4], dwv[4];
  int tid = threadIdx.x;
  for (int i = tid; i < K*F; i += 256) Wl[i] = W[i];
  int f = tid % F;
  int lr = tid / F;
  float vs = atts[f], vd = attd[f];
  const int ntiles = (N_NODES + ROWS - 1)/ROWS;
  for (int t = blockIdx.x; t < ntiles; t += gridDim.x){
    int r0 = t*ROWS;
    __syncthreads();
    for (int i = tid; i < ROWS*K; i += 256){
      int r = i / K, k = i % K;
      int row = r0 + r;
      xl[i] = (row < N_NODES) ? x[row*K + k] : 0.f;
    }
    __syncthreads();
    float acc = 0.f;
    #pragma unroll
    for (int k = 0; k < K; ++k) acc += xl[lr*K + k] * Wl[k*F + f];
    int row = r0 + lr;
    if (row < N_NODES) hb[row*F + f] = f2bf(acc);
    float s = acc*vs, d = acc*vd;
    #pragma unroll
    for (int o = 32; o; o >>= 1){ s += __shfl_down(s, o); d += __shfl_down(d, o); }
    int wv = tid >> 6;
    if ((tid & 63) == 0){ swv[wv] = s; dwv[wv] = d; }
    __syncthreads();
    if (f == 0 && row < N_NODES){
      a_s[row] = swv[2*lr] + swv[2*lr+1];
      a_d[row] = dwv[2*lr] + dwv[2*lr+1];
    }
  }
}

// ---------- layers 2/3: MFMA GEMM h = A(bf16) @ W(->bf16), fused att dots ----------
// A: [N_NODES][128] bf16. W: [128][F] f32 (converted to LDS bf16, [col][k] pad 136).
// 4 waves/block, 64 rows/block. Fragment layout (m92/m97-verified):
//   A: row=lane&15, k=(lane>>4)*8+i (contiguous 16B); B: col=lane&15, same k.
//   D: col=lane&15, row=(lane>>4)*4+reg.
template<int F>
__global__ __launch_bounds__(256) void gemm_mfma_kernel(
    const unsigned short* __restrict__ A, const float* __restrict__ W,
    const float* __restrict__ atts, const float* __restrict__ attd,
    unsigned short* __restrict__ hb, float* __restrict__ a_s, float* __restrict__ a_d)
{
  constexpr int NT = F/16;
  constexpr int KP = 136;
  __shared__ unsigned short Wb[F*KP];
  int tid = threadIdx.x;
  for (int idx = tid; idx < 128*F; idx += 256){
    int k = idx / F, col = idx % F;
    Wb[col*KP + k] = f2bf(W[idx]);
  }
  __syncthreads();
  int wave = tid >> 6, lane = tid & 63;
  int r0w = blockIdx.x*64 + wave*16;
  int arow = r0w + (lane & 15);
  bool av = arow < N_NODES;
  f32x4 acc[NT];
  #pragma unroll
  for (int nt = 0; nt < NT; ++nt) acc[nt] = 0.f;
  #pragma unroll
  for (int step = 0; step < 4; ++step){
    int kbase = step*32 + (lane>>4)*8;
    uint4 araw = av ? *reinterpret_cast<const uint4*>(&A[(size_t)arow*128 + kbase])
                    : make_uint4(0,0,0,0);
    bf16v af = __builtin_bit_cast(bf16v, araw);
    #pragma unroll
    for (int nt = 0; nt < NT; ++nt){
      uint4 braw = *reinterpret_cast<const uint4*>(&Wb[(nt*16 + (lane&15))*KP + kbase]);
      bf16v bfr = __builtin_bit_cast(bf16v, braw);
      acc[nt] = __builtin_amdgcn_mfma_f32_16x16x32_bf16(af, bfr, acc[nt], 0, 0, 0);
    }
  }
  // epilogue
  float ps[4] = {0,0,0,0}, pd[4] = {0,0,0,0};
  #pragma unroll
  for (int nt = 0; nt < NT; ++nt){
    int col = nt*16 + (lane&15);
    float vs = atts[col], vd = attd[col];
    #pragma unroll
    for (int reg = 0; reg < 4; ++reg){
      int row = r0w + (lane>>4)*4 + reg;
      float v = acc[nt][reg];
      if (row < N_NODES) hb[(size_t)row*F + col] = f2bf(v);
      ps[reg] += v*vs;
      pd[reg] += v*vd;
    }
  }
  #pragma unroll
  for (int reg = 0; reg < 4; ++reg){
    float s = ps[reg], d = pd[reg];
    #pragma unroll
    for (int o = 1; o < 16; o <<= 1){ s += __shfl_xor(s, o); d += __shfl_xor(d, o); }
    int row = r0w + (lane>>4)*4 + reg;
    if ((lane & 15) == 0 && row < N_NODES){ a_s[row] = s; a_d[row] = d; }
  }
}

// ---------- per-dst two-phase softmax aggregation, paired gather ----------
// One wave per dst; phase 2 processes 2 edges/iteration (32 lanes each, 8B loads),
// unroll 4 -> up to 8 gather rows in flight.
template<int F, int PERL, bool W32>
__global__ __launch_bounds__(256) void aggregate_kernel(
    const unsigned short* __restrict__ hb,
    const float* __restrict__ a_s, const float* __restrict__ a_d,
    const int2* __restrict__ edges, const int* __restrict__ row_ptr,
    const float* __restrict__ scal, int b, int l,
    const float* __restrict__ bias, float* __restrict__ out32,
    unsigned short* __restrict__ outb)
{
  int wv = threadIdx.x >> 6;
  int lane = threadIdx.x & 63;
  int d = blockIdx.x*4 + wv;
  if (d >= N_NODES) return;
  int sub = lane & 31, half = lane >> 5;
  float c = scal[2+l];
  float ae_self = (scal[b] * (1.0f/N_EDGES)) * c;
  float add_ = a_d[d];
  float m = leaky02(a_s[d] + add_ + ae_self);
  float denom = 1.0f;
  float acc[PERL];
  if (half == 0){
    if (PERL == 4){
      uint2 v = *reinterpret_cast<const uint2*>(&hb[(size_t)d*F + 4*sub]);
      acc[0] = bflo(v.x); acc[1] = bfhi(v.x); acc[2] = bflo(v.y); acc[3] = bfhi(v.y);
    } else {
      unsigned int v = *reinterpret_cast<const unsigned int*>(&hb[(size_t)d*F + 2*sub]);
      acc[0] = bflo(v); acc[1] = bfhi(v);
    }
  } else {
    #pragma unroll
    for (int i = 0; i < PERL; ++i) acc[i] = 0.f;
  }
  int e0 = row_ptr[d], e1 = row_ptr[d+1];
  for (int ch = e0; ch < e1; ch += 128){
    int n = min(128, e1 - ch);
    // phase 1: parallel logits + reductions
    int s0 = 0, s1 = 0;
    float l0 = -1e30f, l1 = -1e30f;
    if (lane < n){
      int2 ed = edges[ch + lane];
      s0 = ed.x;
      l0 = leaky02(a_s[ed.x] + add_ + c*__int_as_float(ed.y));
    }
    if (lane + 64 < n){
      int2 ed = edges[ch + 64 + lane];
      s1 = ed.x;
      l1 = leaky02(a_s[ed.x] + add_ + c*__int_as_float(ed.y));
    }
    float lmax = fmaxf(l0, l1);
    #pragma unroll
    for (int o = 32; o; o >>= 1) lmax = fmaxf(lmax, __shfl_xor(lmax, o));
    float mn = fmaxf(m, lmax);
    float sc = __expf(m - mn);
    denom *= sc;
    #pragma unroll
    for (int i = 0; i < PERL; ++i) acc[i] *= sc;
    m = mn;
    float p0 = (lane < n)      ? __expf(l0 - m) : 0.f;
    float p1 = (lane + 64 < n) ? __expf(l1 - m) : 0.f;
    float ds = p0 + p1;
    #pragma unroll
    for (int o = 32; o; o >>= 1) ds += __shfl_xor(ds, o);
    denom += ds;
    // phase 2: paired gather
    int npair = (n + 1) >> 1;
    int npA = min(npair, 32);
    #pragma unroll 4
    for (int k = 0; k < npA; ++k){
      int idx = 2*k + half;
      int src = __shfl(s0, idx);
      float p = __shfl(p0, idx);
      if (PERL == 4){
        uint2 v = *reinterpret_cast<const uint2*>(&hb[(size_t)src*F + 4*sub]);
        acc[0] += p*bflo(v.x); acc[1] += p*bfhi(v.x); acc[2] += p*bflo(v.y); acc[3] += p*bfhi(v.y);
      } else {
        unsigned int v = *reinterpret_cast<const unsigned int*>(&hb[(size_t)src*F + 2*sub]);
        acc[0] += p*bflo(v); acc[1] += p*bfhi(v);
      }
    }
    #pragma unroll 4
    for (int k = 32; k < npair; ++k){
      int idx = 2*k + half - 64;
      int src = __shfl(s1, idx);
      float p = __shfl(p1, idx);
      if (PERL == 4){
        uint2 v = *reinterpret_cast<const uint2*>(&hb[(size_t)src*F + 4*sub]);
        acc[0] += p*bflo(v.x); acc[1] += p*bfhi(v.x); acc[2] += p*bflo(v.y); acc[3] += p*bfhi(v.y);
      } else {
        unsigned int v = *reinterpret_cast<const unsigned int*>(&hb[(size_t)src*F + 2*sub]);
        acc[0] += p*bflo(v); acc[1] += p*bfhi(v);
      }
    }
  }
  float inv = 1.0f/denom;
  float vv[PERL];
  #pragma unroll
  for (int i = 0; i < PERL; ++i){
    float tot = acc[i] + __shfl_xor(acc[i], 32);
    vv[i] = eluf(tot*inv + bias[PERL*sub + i]);
  }
  if (half == 0){
    if (W32){
      if (PERL == 4) *reinterpret_cast<float4*>(&out32[(size_t)d*F + 4*sub]) = make_float4(vv[0],vv[1],vv[2],vv[3]);
      else           *reinterpret_cast<float2*>(&out32[(size_t)d*F + 2*sub]) = make_float2(vv[0],vv[1]);
    }
  } else {
    if (PERL == 4){
      uint2 o;
      o.x = (unsigned int)f2bf(vv[0]) | ((unsigned int)f2bf(vv[1]) << 16);
      o.y = (unsigned int)f2bf(vv[2]) | ((unsigned int)f2bf(vv[3]) << 16);
      *reinterpret_cast<uint2*>(&outb[(size_t)d*F + 4*sub]) = o;
    } else {
      unsigned int o = (unsigned int)f2bf(vv[0]) | ((unsigned int)f2bf(vv[1]) << 16);
      *reinterpret_cast<unsigned int*>(&outb[(size_t)d*F + 2*sub]) = o;
    }
  }
}

// ---------- sorted-batch graph boundaries ----------
__global__ void bounds_kernel(const int* __restrict__ batch, int* __restrict__ gb){
  int g = blockIdx.x*blockDim.x + threadIdx.x;
  if (g > N_GRAPHS) return;
  int lo = 0, hi = N_NODES;
  while (lo < hi){ int mid = (lo+hi) >> 1; if (batch[mid] < g) lo = mid+1; else hi = mid; }
  gb[g] = lo;
}

__global__ __launch_bounds__(256) void pool_mean_kernel(const float* __restrict__ x,
                                                        const int* __restrict__ gb,
                                                        float* __restrict__ mean){
  int g = blockIdx.x;
  int s = gb[g], e = gb[g+1];
  int f = threadIdx.x & 63, rg = threadIdx.x >> 6;
  float acc = 0.f;
  for (int r = s + rg; r < e; r += 4) acc += x[r*64 + f];
  __shared__ float red[4][64];
  red[rg][f] = acc;
  __syncthreads();
  if (rg == 0){
    float t = red[0][f] + red[1][f] + red[2][f] + red[3][f];
    mean[g*64 + f] = t / fmaxf((float)(e - s), 1.0f);
  }
}

__global__ void final_kernel(const float* __restrict__ mean,
                             const float* __restrict__ xn, const float* __restrict__ linW,
                             const float* __restrict__ linb, float* __restrict__ out){
  __shared__ float Wl[80*64];
  int tid = threadIdx.x;
  for (int i = tid; i < 80*64; i += 256) Wl[i] = linW[i];
  __syncthreads();
  int gl = tid >> 6, j = tid & 63;
  int g = blockIdx.x*4 + gl;
  if (g >= N_GRAPHS) return;
  float acc = linb[j];
  #pragma unroll 8
  for (int k = 0; k < 64; ++k) acc += mean[g*64+k] * Wl[k*64 + j];
  #pragma unroll
  for (int k = 0; k < 16; ++k) acc += xn[g*16+k] * Wl[(64+k)*64 + j];
  out[g*64 + j] = acc;
}

extern "C" void kernel_launch(void* const* d_in, const int* in_sizes, int n_in,
                              void* d_out, int out_size, void* d_ws, size_t ws_size,
                              hipStream_t stream)
{
  const float* x1   = (const float*)d_in[0];
  const float* x2   = (const float*)d_in[1];
  const int*   ei1  = (const int*)d_in[2];
  const int*   ei2  = (const int*)d_in[3];
  const int*   bat1 = (const int*)d_in[4];
  const int*   bat2 = (const int*)d_in[5];
  const float* xn1  = (const float*)d_in[6];
  const float* xn2  = (const float*)d_in[7];
  const float* ec1  = (const float*)d_in[8];
  const float* ec2  = (const float*)d_in[9];
  const float* W[3]   = {(const float*)d_in[10], (const float*)d_in[16], (const float*)d_in[22]};
  const float* as_[3] = {(const float*)d_in[11], (const float*)d_in[17], (const float*)d_in[23]};
  const float* ad_[3] = {(const float*)d_in[12], (const float*)d_in[18], (const float*)d_in[24]};
  const float* We[3]  = {(const float*)d_in[13], (const float*)d_in[19], (const float*)d_in[25]};
  const float* ae[3]  = {(const float*)d_in[14], (const float*)d_in[20], (const float*)d_in[26]};
  const float* bb[3]  = {(const float*)d_in[15], (const float*)d_in[21], (const float*)d_in[27]};
  const float* linW = (const float*)d_in[28];
  const float* linb = (const float*)d_in[29];
  float* out = (float*)d_out;

  char* ws = (char*)d_ws;
  size_t off = 0;
  auto alloc = [&](size_t bytes)->char*{
    char* p = ws + off;
    off = (off + bytes + 255) & ~(size_t)255;
    return p;
  };
  unsigned short* hbA = (unsigned short*)alloc((size_t)N_NODES*128*2); // gather source
  unsigned short* hbB = (unsigned short*)alloc((size_t)N_NODES*128*2); // aggregate out / GEMM A
  float* buf0 = (float*)alloc((size_t)N_NODES*64*4);                   // layer-3 f32 out
  float* aS   = (float*)alloc((size_t)N_NODES*4);
  float* aD   = (float*)alloc((size_t)N_NODES*4);
  int* deg    = (int*)alloc((size_t)N_NODES*4);
  int* rowp   = (int*)alloc((size_t)(N_NODES+4)*4);
  int* cur    = (int*)alloc((size_t)N_NODES*4);
  int2* edg   = (int2*)alloc((size_t)N_EDGES*8);
  float* mean = (float*)alloc((size_t)N_GRAPHS*64*4);
  int* gb     = (int*)alloc((size_t)(N_GRAPHS+8)*4);
  float* scal = (float*)alloc(64);

  hipMemsetAsync(scal, 0, 64, stream);
  prep_c_kernel<<<1, 256, 0, stream>>>(We[0], ae[0], We[1], ae[1], We[2], ae[2], scal);

  const float* xin[2]  = {x1, x2};
  const int*   ei[2]   = {ei1, ei2};
  const int*   bat[2]  = {bat1, bat2};
  const float* xn[2]   = {xn1, xn2};
  const float* ec[2]   = {ec1, ec2};

  for (int b = 0; b < 2; ++b){
    const int* srcp = ei[b];
    const int* dstp = ei[b] + N_EDGES;
    hipMemsetAsync(deg, 0, (size_t)N_NODES*4, stream);
    reduce_sum_kernel<<<1024, 256, 0, stream>>>(ec[b], N_EDGES, scal + b);
    count_deg_kernel<<<(N_EDGES+255)/256, 256, 0, stream>>>(dstp, deg);
    scan_kernel<<<1, 1024, 0, stream>>>(deg, rowp, cur);
    scatter_kernel<<<(N_EDGES+255)/256, 256, 0, stream>>>(srcp, dstp, ec[b], cur, edg);
    bounds_kernel<<<2, 256, 0, stream>>>(bat[b], gb);

    // layer 1: K=7 -> F=128
    node_linear1_kernel<7,128><<<1024, 256, 0, stream>>>(
        xin[b], W[0], as_[0], ad_[0], hbA, aS, aD);
    aggregate_kernel<128,4,false><<<N_NODES/4, 256, 0, stream>>>(
        hbA, aS, aD, edg, rowp, scal, b, 0, bb[0], nullptr, hbB);

    // layer 2: MFMA 128->128
    gemm_mfma_kernel<128><<<(N_NODES+63)/64, 256, 0, stream>>>(
        hbB, W[1], as_[1], ad_[1], hbA, aS, aD);
    aggregate_kernel<128,4,false><<<N_NODES/4, 256, 0, stream>>>(
        hbA, aS, aD, edg, rowp, scal, b, 1, bb[1], nullptr, hbB);

    // layer 3: MFMA 128->64
    gemm_mfma_kernel<64><<<(N_NODES+63)/64, 256, 0, stream>>>(
        hbB, W[2], as_[2], ad_[2], hbA, aS, aD);
    aggregate_kernel<64,2,true><<<N_NODES/4, 256, 0, stream>>>(
        hbA, aS, aD, edg, rowp, scal, b, 2, bb[2], buf0, hbB);

    pool_mean_kernel<<<N_GRAPHS, 256, 0, stream>>>(buf0, gb, mean);
    final_kernel<<<(N_GRAPHS+3)/4, 256, 0, stream>>>(mean, xn[b], linW, linb, out + (size_t)b*N_GRAPHS*64);
  }
}

// Round 4
// 372.180 us; speedup vs baseline: 2.8789x; 1.4697x over previous
//
#include <hip/hip_runtime.h>
#include <hip/hip_bf16.h>

#define N_NODES 20000
#define N_EDGES 640000
#define N_GRAPHS 256
#define NPART 2500

typedef short bf16v __attribute__((ext_vector_type(8)));   // 8 bf16 (4 VGPRs)
typedef float f32x4 __attribute__((ext_vector_type(4)));

__device__ __forceinline__ float leaky02(float x){ return x > 0.f ? x : 0.2f*x; }
__device__ __forceinline__ float eluf(float x){ return x > 0.f ? x : (__expf(x) - 1.f); }
__device__ __forceinline__ unsigned short f2bf(float x){
  __hip_bfloat16 t = __float2bfloat16(x);
  return *reinterpret_cast<unsigned short*>(&t);
}
__device__ __forceinline__ float bflo(unsigned int u){ return __uint_as_float(u << 16); }
__device__ __forceinline__ float bfhi(unsigned int u){ return __uint_as_float(u & 0xffff0000u); }

// ---------- scalar prep: c_l = dot(We_l, ae_l) ----------
__global__ void prep_c_kernel(const float* __restrict__ We1, const float* __restrict__ ae1,
                              const float* __restrict__ We2, const float* __restrict__ ae2,
                              const float* __restrict__ We3, const float* __restrict__ ae3,
                              float* __restrict__ scal){
  int tid = threadIdx.x;
  int wv = tid >> 6, lane = tid & 63;
  if (wv < 3){
    const float* We = wv==0 ? We1 : (wv==1 ? We2 : We3);
    const float* ae = wv==0 ? ae1 : (wv==1 ? ae2 : ae3);
    int F = (wv==2) ? 64 : 128;
    float s = 0.f;
    for (int i = lane; i < F; i += 64) s += We[i]*ae[i];
    for (int o = 32; o; o >>= 1) s += __shfl_down(s, o);
    if (lane == 0) scal[2+wv] = s;
  }
}

// ---------- edge prep: degree count + edge_col partial sums, both branches ----------
__global__ __launch_bounds__(256) void edge_prep_kernel(
    const int* __restrict__ ei0, const int* __restrict__ ei1,
    const float* __restrict__ ec0, const float* __restrict__ ec1,
    int* __restrict__ deg, float* __restrict__ part)
{
  int b = blockIdx.y;
  const int* dstp = (b ? ei1 : ei0) + N_EDGES;
  const float* ec = b ? ec1 : ec0;
  int i = blockIdx.x*256 + threadIdx.x;
  if (i < N_EDGES) atomicAdd(&deg[b*N_NODES + dstp[i]], 1);
  float v = (i < N_EDGES) ? ec[i] : 0.f;
  for (int o = 32; o; o >>= 1) v += __shfl_down(v, o);
  __shared__ float wr[4];
  int lane = threadIdx.x & 63, wv = threadIdx.x >> 6;
  if (lane == 0) wr[wv] = v;
  __syncthreads();
  if (threadIdx.x == 0) part[b*NPART + blockIdx.x] = wr[0]+wr[1]+wr[2]+wr[3];
}

// ---------- scan + ec-sum + graph bounds (one block per branch) ----------
__global__ __launch_bounds__(1024) void scan_kernel(
    const int* __restrict__ deg, const float* __restrict__ part,
    const int* __restrict__ bat0, const int* __restrict__ bat1,
    int* __restrict__ rowp, int* __restrict__ cur, int* __restrict__ gb,
    float* __restrict__ scal)
{
  int b = blockIdx.x;
  const int* degb = deg + b*N_NODES;
  int* rowb = rowp + b*(N_NODES+1);
  int* curb = cur + b*N_NODES;
  int tid = threadIdx.x;
  // ec sum of partials
  {
    float s = 0.f;
    for (int i = tid; i < NPART; i += 1024) s += part[b*NPART + i];
    for (int o = 32; o; o >>= 1) s += __shfl_down(s, o);
    __shared__ float fr[16];
    if ((tid & 63) == 0) fr[tid >> 6] = s;
    __syncthreads();
    if (tid == 0){
      float t = 0.f;
      for (int i = 0; i < 16; ++i) t += fr[i];
      scal[b] = t;
    }
  }
  // graph bounds (batch sorted)
  {
    const int* batch = b ? bat1 : bat0;
    int* gbb = gb + b*257;
    if (tid <= N_GRAPHS){
      int g = tid, lo = 0, hi = N_NODES;
      while (lo < hi){ int mid = (lo+hi) >> 1; if (batch[mid] < g) lo = mid+1; else hi = mid; }
      gbb[g] = lo;
    }
  }
  // prefix scan of degrees
  __shared__ int sums[1024];
  const int CH = (N_NODES + 1023)/1024; // 20
  int base = tid*CH;
  int s = 0;
  #pragma unroll
  for (int i = 0; i < CH; ++i){ int idx = base+i; if (idx < N_NODES) s += degb[idx]; }
  sums[tid] = s;
  __syncthreads();
  for (int d = 1; d < 1024; d <<= 1){
    int v = (tid >= d) ? sums[tid-d] : 0;
    __syncthreads();
    sums[tid] += v;
    __syncthreads();
  }
  int off = sums[tid] - s;
  for (int i = 0; i < CH; ++i){
    int idx = base+i;
    if (idx < N_NODES){ int c = degb[idx]; rowb[idx] = off; curb[idx] = off; off += c; }
  }
  if (tid == 1023) rowb[N_NODES] = sums[1023];
}

__global__ __launch_bounds__(256) void scatter_kernel(
    const int* __restrict__ ei0, const int* __restrict__ ei1,
    const float* __restrict__ ec0, const float* __restrict__ ec1,
    int* __restrict__ cur, int2* __restrict__ edg)
{
  int b = blockIdx.y;
  const int* srcp = (b ? ei1 : ei0);
  const int* dstp = srcp + N_EDGES;
  const float* ec = b ? ec1 : ec0;
  int i = blockIdx.x*256 + threadIdx.x;
  if (i < N_EDGES){
    int d = dstp[i];
    int pos = atomicAdd(&cur[b*N_NODES + d], 1);
    edg[(size_t)b*N_EDGES + pos] = make_int2(srcp[i], __float_as_int(ec[i]));
  }
}

// ---------- layer 1: K=7 scalar GEMM + att dots, bf16 out, both branches ----------
template<int K, int F>
__global__ __launch_bounds__(256) void node_linear1_kernel(
    const float* __restrict__ x0, const float* __restrict__ x1,
    const float* __restrict__ W,
    const float* __restrict__ atts, const float* __restrict__ attd,
    unsigned short* __restrict__ hbAll, float* __restrict__ aSAll, float* __restrict__ aDAll)
{
  int b = blockIdx.y;
  const float* x = b ? x1 : x0;
  unsigned short* hb = hbAll + (size_t)b*N_NODES*128;
  float* a_s = aSAll + b*N_NODES;
  float* a_d = aDAll + b*N_NODES;
  constexpr int ROWS = 256 / F; // 2
  __shared__ float Wl[K*F];
  __shared__ float xl[ROWS*K];
  __shared__ float swv[4], dwv[4];
  int tid = threadIdx.x;
  for (int i = tid; i < K*F; i += 256) Wl[i] = W[i];
  int f = tid % F;
  int lr = tid / F;
  float vs = atts[f], vd = attd[f];
  const int ntiles = (N_NODES + ROWS - 1)/ROWS;
  for (int t = blockIdx.x; t < ntiles; t += gridDim.x){
    int r0 = t*ROWS;
    __syncthreads();
    for (int i = tid; i < ROWS*K; i += 256){
      int r = i / K, k = i % K;
      int row = r0 + r;
      xl[i] = (row < N_NODES) ? x[row*K + k] : 0.f;
    }
    __syncthreads();
    float acc = 0.f;
    #pragma unroll
    for (int k = 0; k < K; ++k) acc += xl[lr*K + k] * Wl[k*F + f];
    int row = r0 + lr;
    if (row < N_NODES) hb[row*F + f] = f2bf(acc);
    float s = acc*vs, d = acc*vd;
    #pragma unroll
    for (int o = 32; o; o >>= 1){ s += __shfl_down(s, o); d += __shfl_down(d, o); }
    int wv = tid >> 6;
    if ((tid & 63) == 0){ swv[wv] = s; dwv[wv] = d; }
    __syncthreads();
    if (f == 0 && row < N_NODES){
      a_s[row] = swv[2*lr] + swv[2*lr+1];
      a_d[row] = dwv[2*lr] + dwv[2*lr+1];
    }
  }
}

// ---------- layers 2/3: MFMA GEMM (A bf16 -> bf16 out), fused att dots, both branches ----------
template<int F>
__global__ __launch_bounds__(256) void gemm_mfma_kernel(
    const unsigned short* __restrict__ AAll, const float* __restrict__ W,
    const float* __restrict__ atts, const float* __restrict__ attd,
    unsigned short* __restrict__ hbAll, float* __restrict__ aSAll, float* __restrict__ aDAll)
{
  int b = blockIdx.y;
  const unsigned short* A = AAll + (size_t)b*N_NODES*128;
  unsigned short* hb = hbAll + (size_t)b*N_NODES*128;
  float* a_s = aSAll + b*N_NODES;
  float* a_d = aDAll + b*N_NODES;
  constexpr int NT = F/16;
  constexpr int KP = 136;
  __shared__ unsigned short Wb[F*KP];
  int tid = threadIdx.x;
  for (int idx = tid; idx < 128*F; idx += 256){
    int k = idx / F, col = idx % F;
    Wb[col*KP + k] = f2bf(W[idx]);
  }
  __syncthreads();
  int wave = tid >> 6, lane = tid & 63;
  int r0w = blockIdx.x*64 + wave*16;
  int arow = r0w + (lane & 15);
  bool av = arow < N_NODES;
  f32x4 acc[NT];
  #pragma unroll
  for (int nt = 0; nt < NT; ++nt) acc[nt] = 0.f;
  #pragma unroll
  for (int step = 0; step < 4; ++step){
    int kbase = step*32 + (lane>>4)*8;
    uint4 araw = av ? *reinterpret_cast<const uint4*>(&A[(size_t)arow*128 + kbase])
                    : make_uint4(0,0,0,0);
    bf16v af = __builtin_bit_cast(bf16v, araw);
    #pragma unroll
    for (int nt = 0; nt < NT; ++nt){
      uint4 braw = *reinterpret_cast<const uint4*>(&Wb[(nt*16 + (lane&15))*KP + kbase]);
      bf16v bfr = __builtin_bit_cast(bf16v, braw);
      acc[nt] = __builtin_amdgcn_mfma_f32_16x16x32_bf16(af, bfr, acc[nt], 0, 0, 0);
    }
  }
  float ps[4] = {0,0,0,0}, pd[4] = {0,0,0,0};
  #pragma unroll
  for (int nt = 0; nt < NT; ++nt){
    int col = nt*16 + (lane&15);
    float vs = atts[col], vd = attd[col];
    #pragma unroll
    for (int reg = 0; reg < 4; ++reg){
      int row = r0w + (lane>>4)*4 + reg;
      float v = acc[nt][reg];
      if (row < N_NODES) hb[(size_t)row*F + col] = f2bf(v);
      ps[reg] += v*vs;
      pd[reg] += v*vd;
    }
  }
  #pragma unroll
  for (int reg = 0; reg < 4; ++reg){
    float s = ps[reg], d = pd[reg];
    #pragma unroll
    for (int o = 1; o < 16; o <<= 1){ s += __shfl_xor(s, o); d += __shfl_xor(d, o); }
    int row = r0w + (lane>>4)*4 + reg;
    if ((lane & 15) == 0 && row < N_NODES){ a_s[row] = s; a_d[row] = d; }
  }
}

// ---------- aggregation: one wave/dst, 4 edges/iter (16 lanes x 16B each) ----------
template<int F, bool W32>
__global__ __launch_bounds__(256) void aggregate_kernel(
    const unsigned short* __restrict__ hbAll,
    const float* __restrict__ aSAll, const float* __restrict__ aDAll,
    const int2* __restrict__ edgAll, const int* __restrict__ rowpAll,
    const float* __restrict__ scal, int l,
    const float* __restrict__ bias,
    float* __restrict__ out32All, unsigned short* __restrict__ outbAll)
{
  constexpr int PERL = F/16;  // 8 (F=128) or 4 (F=64)
  int b = blockIdx.y;
  const unsigned short* hb = hbAll + (size_t)b*N_NODES*128;
  const float* a_s = aSAll + b*N_NODES;
  const float* a_d = aDAll + b*N_NODES;
  const int2* edges = edgAll + (size_t)b*N_EDGES;
  const int* rowp = rowpAll + b*(N_NODES+1);
  int wv = threadIdx.x >> 6;
  int lane = threadIdx.x & 63;
  int d = blockIdx.x*4 + wv;
  if (d >= N_NODES) return;
  int sub = lane & 15, grp = lane >> 4;
  float c = scal[2+l];
  float ae_self = (scal[b] * (1.0f/N_EDGES)) * c;
  float add_ = a_d[d];
  float m = leaky02(a_s[d] + add_ + ae_self);
  float denom = 1.0f;
  float acc[PERL];
  #pragma unroll
  for (int i = 0; i < PERL; ++i) acc[i] = 0.f;
  if (grp == 0){
    if (PERL == 8){
      uint4 q = *reinterpret_cast<const uint4*>(&hb[(size_t)d*F + 8*sub]);
      acc[0]=bflo(q.x); acc[1]=bfhi(q.x); acc[2]=bflo(q.y); acc[3]=bfhi(q.y);
      acc[4]=bflo(q.z); acc[5]=bfhi(q.z); acc[6]=bflo(q.w); acc[7]=bfhi(q.w);
    } else {
      uint2 q = *reinterpret_cast<const uint2*>(&hb[(size_t)d*F + 4*sub]);
      acc[0]=bflo(q.x); acc[1]=bfhi(q.x); acc[2]=bflo(q.y); acc[3]=bfhi(q.y);
    }
  }
  int e0 = rowp[d], e1 = rowp[d+1];
  for (int ch = e0; ch < e1; ch += 64){
    int n = min(64, e1 - ch);
    // phase 1: parallel logits + reductions
    int s0 = 0;
    float l0 = -1e30f;
    if (lane < n){
      int2 ed = edges[ch + lane];
      s0 = ed.x;
      l0 = leaky02(a_s[ed.x] + add_ + c*__int_as_float(ed.y));
    }
    float lmax = l0;
    #pragma unroll
    for (int o = 32; o; o >>= 1) lmax = fmaxf(lmax, __shfl_xor(lmax, o));
    float mn = fmaxf(m, lmax);
    float sc = __expf(m - mn);
    denom *= sc;
    #pragma unroll
    for (int i = 0; i < PERL; ++i) acc[i] *= sc;
    m = mn;
    float p0 = (lane < n) ? __expf(l0 - m) : 0.f;
    float ds = p0;
    #pragma unroll
    for (int o = 32; o; o >>= 1) ds += __shfl_xor(ds, o);
    denom += ds;
    // phase 2: 4 edges per iteration (grp = edge slot, 16 lanes each)
    int niter = (n + 3) >> 2;
    #pragma unroll 2
    for (int k = 0; k < niter; ++k){
      int idx = 4*k + grp;           // may exceed n-1 on tail: p=0 there
      int src = __shfl(s0, idx);
      float p = __shfl(p0, idx);
      if (PERL == 8){
        uint4 q = *reinterpret_cast<const uint4*>(&hb[(size_t)src*F + 8*sub]);
        acc[0]+=p*bflo(q.x); acc[1]+=p*bfhi(q.x); acc[2]+=p*bflo(q.y); acc[3]+=p*bfhi(q.y);
        acc[4]+=p*bflo(q.z); acc[5]+=p*bfhi(q.z); acc[6]+=p*bflo(q.w); acc[7]+=p*bfhi(q.w);
      } else {
        uint2 q = *reinterpret_cast<const uint2*>(&hb[(size_t)src*F + 4*sub]);
        acc[0]+=p*bflo(q.x); acc[1]+=p*bfhi(q.x); acc[2]+=p*bflo(q.y); acc[3]+=p*bfhi(q.y);
      }
    }
  }
  // cross-group reduce (grps hold partial sums of same features)
  #pragma unroll
  for (int i = 0; i < PERL; ++i){
    acc[i] += __shfl_xor(acc[i], 16);
    acc[i] += __shfl_xor(acc[i], 32);
  }
  float inv = 1.0f/denom;
  float vv[PERL];
  #pragma unroll
  for (int i = 0; i < PERL; ++i) vv[i] = eluf(acc[i]*inv + bias[PERL*sub + i]);
  if (grp == 0){
    if (W32){
      float* out32 = out32All + (size_t)b*N_NODES*64;
      *reinterpret_cast<float4*>(&out32[(size_t)d*64 + 4*sub]) = make_float4(vv[0],vv[1],vv[2],vv[3]);
    } else {
      unsigned short* outb = outbAll + (size_t)b*N_NODES*128;
      if (PERL == 8){
        uint4 o;
        o.x = (unsigned int)f2bf(vv[0]) | ((unsigned int)f2bf(vv[1]) << 16);
        o.y = (unsigned int)f2bf(vv[2]) | ((unsigned int)f2bf(vv[3]) << 16);
        o.z = (unsigned int)f2bf(vv[4]) | ((unsigned int)f2bf(vv[5]) << 16);
        o.w = (unsigned int)f2bf(vv[6]) | ((unsigned int)f2bf(vv[7]) << 16);
        *reinterpret_cast<uint4*>(&outb[(size_t)d*F + 8*sub]) = o;
      } else {
        uint2 o;
        o.x = (unsigned int)f2bf(vv[0]) | ((unsigned int)f2bf(vv[1]) << 16);
        o.y = (unsigned int)f2bf(vv[2]) | ((unsigned int)f2bf(vv[3]) << 16);
        *reinterpret_cast<uint2*>(&outb[(size_t)d*F + 4*sub]) = o;
      }
    }
  }
}

// ---------- fused mean-pool + final linear ----------
__global__ __launch_bounds__(256) void pool_final_kernel(
    const float* __restrict__ buf0, const int* __restrict__ gb,
    const float* __restrict__ xn0, const float* __restrict__ xn1,
    const float* __restrict__ linW, const float* __restrict__ linb,
    float* __restrict__ out)
{
  int bg = blockIdx.x;
  int b = bg >> 8, g = bg & 255;
  __shared__ float Wl[80*64];
  __shared__ float red[4][64];
  __shared__ float mf[64];
  int tid = threadIdx.x;
  for (int i = tid; i < 80*64; i += 256) Wl[i] = linW[i];
  const float* x = buf0 + (size_t)b*N_NODES*64;
  const int* gbb = gb + b*257;
  int s = gbb[g], e = gbb[g+1];
  int f = tid & 63, rg = tid >> 6;
  float acc = 0.f;
  for (int r = s + rg; r < e; r += 4) acc += x[r*64 + f];
  red[rg][f] = acc;
  __syncthreads();
  if (rg == 0)
    mf[f] = (red[0][f]+red[1][f]+red[2][f]+red[3][f]) / fmaxf((float)(e - s), 1.0f);
  __syncthreads();
  if (tid < 64){
    int j = tid;
    const float* xn = b ? xn1 : xn0;
    float a2 = linb[j];
    #pragma unroll 8
    for (int k = 0; k < 64; ++k) a2 += mf[k] * Wl[k*64 + j];
    #pragma unroll
    for (int k = 0; k < 16; ++k) a2 += xn[g*16+k] * Wl[(64+k)*64 + j];
    out[(size_t)(b*N_GRAPHS + g)*64 + j] = a2;
  }
}

extern "C" void kernel_launch(void* const* d_in, const int* in_sizes, int n_in,
                              void* d_out, int out_size, void* d_ws, size_t ws_size,
                              hipStream_t stream)
{
  const float* x1   = (const float*)d_in[0];
  const float* x2   = (const float*)d_in[1];
  const int*   ei1  = (const int*)d_in[2];
  const int*   ei2  = (const int*)d_in[3];
  const int*   bat1 = (const int*)d_in[4];
  const int*   bat2 = (const int*)d_in[5];
  const float* xn1  = (const float*)d_in[6];
  const float* xn2  = (const float*)d_in[7];
  const float* ec1  = (const float*)d_in[8];
  const float* ec2  = (const float*)d_in[9];
  const float* W[3]   = {(const float*)d_in[10], (const float*)d_in[16], (const float*)d_in[22]};
  const float* as_[3] = {(const float*)d_in[11], (const float*)d_in[17], (const float*)d_in[23]};
  const float* ad_[3] = {(const float*)d_in[12], (const float*)d_in[18], (const float*)d_in[24]};
  const float* We[3]  = {(const float*)d_in[13], (const float*)d_in[19], (const float*)d_in[25]};
  const float* ae[3]  = {(const float*)d_in[14], (const float*)d_in[20], (const float*)d_in[26]};
  const float* bb[3]  = {(const float*)d_in[15], (const float*)d_in[21], (const float*)d_in[27]};
  const float* linW = (const float*)d_in[28];
  const float* linb = (const float*)d_in[29];
  float* out = (float*)d_out;

  char* ws = (char*)d_ws;
  size_t off = 0;
  auto alloc = [&](size_t bytes)->char*{
    char* p = ws + off;
    off = (off + bytes + 255) & ~(size_t)255;
    return p;
  };
  unsigned short* hbA = (unsigned short*)alloc((size_t)2*N_NODES*128*2);
  unsigned short* hbB = (unsigned short*)alloc((size_t)2*N_NODES*128*2);
  float* buf0 = (float*)alloc((size_t)2*N_NODES*64*4);
  float* aS   = (float*)alloc((size_t)2*N_NODES*4);
  float* aD   = (float*)alloc((size_t)2*N_NODES*4);
  int* deg    = (int*)alloc((size_t)2*N_NODES*4);
  int* rowp   = (int*)alloc((size_t)2*(N_NODES+1)*4);
  int* cur    = (int*)alloc((size_t)2*N_NODES*4);
  int2* edg   = (int2*)alloc((size_t)2*N_EDGES*8);
  float* part = (float*)alloc((size_t)2*NPART*4);
  int* gb     = (int*)alloc((size_t)2*257*4);
  float* scal = (float*)alloc(64);

  hipMemsetAsync(deg, 0, (size_t)2*N_NODES*4, stream);
  prep_c_kernel<<<1, 256, 0, stream>>>(We[0], ae[0], We[1], ae[1], We[2], ae[2], scal);
  edge_prep_kernel<<<dim3(NPART,2), 256, 0, stream>>>(ei1, ei2, ec1, ec2, deg, part);
  scan_kernel<<<2, 1024, 0, stream>>>(deg, part, bat1, bat2, rowp, cur, gb, scal);
  scatter_kernel<<<dim3(NPART,2), 256, 0, stream>>>(ei1, ei2, ec1, ec2, cur, edg);

  // layer 1: K=7 -> F=128
  node_linear1_kernel<7,128><<<dim3(1024,2), 256, 0, stream>>>(
      x1, x2, W[0], as_[0], ad_[0], hbA, aS, aD);
  aggregate_kernel<128,false><<<dim3(N_NODES/4,2), 256, 0, stream>>>(
      hbA, aS, aD, edg, rowp, scal, 0, bb[0], nullptr, hbB);

  // layer 2: MFMA 128->128
  gemm_mfma_kernel<128><<<dim3((N_NODES+63)/64,2), 256, 0, stream>>>(
      hbB, W[1], as_[1], ad_[1], hbA, aS, aD);
  aggregate_kernel<128,false><<<dim3(N_NODES/4,2), 256, 0, stream>>>(
      hbA, aS, aD, edg, rowp, scal, 1, bb[1], nullptr, hbB);

  // layer 3: MFMA 128->64
  gemm_mfma_kernel<64><<<dim3((N_NODES+63)/64,2), 256, 0, stream>>>(
      hbB, W[2], as_[2], ad_[2], hbA, aS, aD);
  aggregate_kernel<64,true><<<dim3(N_NODES/4,2), 256, 0, stream>>>(
      hbA, aS, aD, edg, rowp, scal, 2, bb[2], buf0, nullptr);

  pool_final_kernel<<<2*N_GRAPHS, 256, 0, stream>>>(
      buf0, gb, xn1, xn2, linW, linb, out);
}